// Round 8
// baseline (72.866 us; speedup 1.0000x reference)
//
#include <hip/hip_runtime.h>

// PCN reduced recurrence (math validated R1/R5-R7, absmax 0.0). Only S[13],
// S[14], Wk[13], Wg matter; out = [initial S14 ; Wg after 10 cycles].
//
//   C  = relu(S14) @ Wk13^T          (constant)   [3-term split-bf16 MFMA]
//   Rs = 0.01 * (S14^T > 0)          (constant)
//   loop:  e = s - C ; g = W^T e     [2-term split-bf16 MFMA]
//          W = e.*Rs ; s += 0.01*(relu'(s)-e).*g
//
// R8 changes (structural dead-code + setup-latency):
//  - Cycle 10's matmul/s-update/staging are unobservable: outputs need only
//    wn = (s-C).*Rs of the 10th cycle. Loop runs 9 full iterations + a
//    3-op tail. Same op order for wn -> bit-identical, absmax stays 0.0.
//  - All global loads (S13, Wg, Rs-rows, Wk13-row, and the 8 S14 A-rows for
//    the C-precompute) issue as ONE early burst; cold-HBM latency overlaps
//    the split-pack VALU instead of serializing mid-setup.
//  - R7 structure kept: 8 waves (2/SIMD), wave w owns column-group (w&3),
//    m-half (w>>2); one barrier/iter, double-buffered packed LDS tiles.

typedef float  f32x4  __attribute__((ext_vector_type(4)));
typedef short  bf16x8 __attribute__((ext_vector_type(8)));

static constexpr float LRc = 0.01f;

union Frag { int i[4]; bf16x8 v; };

__device__ __forceinline__ unsigned hi16(float x) {
    return __float_as_uint(x) & 0xFFFF0000u;
}
__device__ __forceinline__ int pk2(unsigned ha, unsigned hb) {
    return (int)((ha >> 16) | hb);   // a -> low bf16, b -> high bf16
}

// 2-term split of 4 consecutive c-values -> one 16B quad {h01, h23, l01, l23}
__device__ __forceinline__ int4 split2pack(float v0, float v1, float v2, float v3) {
    unsigned h0 = hi16(v0), h1 = hi16(v1), h2 = hi16(v2), h3 = hi16(v3);
    float r0 = v0 - __uint_as_float(h0);
    float r1 = v1 - __uint_as_float(h1);
    float r2 = v2 - __uint_as_float(h2);
    float r3 = v3 - __uint_as_float(h3);
    return make_int4(pk2(h0, h1), pk2(h2, h3),
                     pk2(hi16(r0), hi16(r1)), pk2(hi16(r2), hi16(r3)));
}

// 3-term split of 8 consecutive k-values into three bf16x8 fragments
__device__ __forceinline__ void split3pack8(const float v[8],
                                            bf16x8& H, bf16x8& M, bf16x8& L) {
    Frag fh, fm, fl;
    #pragma unroll
    for (int p = 0; p < 4; ++p) {
        unsigned ha = hi16(v[2*p]),   hb = hi16(v[2*p+1]);
        float ra = v[2*p]   - __uint_as_float(ha);
        float rb = v[2*p+1] - __uint_as_float(hb);
        unsigned ma = hi16(ra), mb = hi16(rb);
        float sa = ra - __uint_as_float(ma);
        float sb = rb - __uint_as_float(mb);
        fh.i[p] = pk2(ha, hb);
        fm.i[p] = pk2(ma, mb);
        fl.i[p] = pk2(hi16(sa), hi16(sb));
    }
    H = fh.v; M = fm.v; L = fl.v;
}

__device__ __forceinline__ bf16x8 mkfrag(int a, int b, int c, int d) {
    Frag f; f.i[0] = a; f.i[1] = b; f.i[2] = c; f.i[3] = d; return f.v;
}

#define MFMA __builtin_amdgcn_mfma_f32_16x16x32_bf16

__global__ __launch_bounds__(512, 2)
void pcn_kernel(const float* __restrict__ S,    // (15,64,64)
                const float* __restrict__ Wk,   // (14,64,64)
                const float* __restrict__ Wg,   // (64,64)
                float* __restrict__ out)        // 8192 floats
{
    if (blockIdx.x == 1) {
        // out[0:4096] = S[14] (never updated by the reference)
        const float4* src = (const float4*)(S + 14 * 4096);
        float4* dst = (float4*)out;
        #pragma unroll
        for (int k = 0; k < 2; ++k)
            dst[threadIdx.x + (k << 9)] = src[threadIdx.x + (k << 9)];
        return;
    }

    // packed operand tiles: [buf][row][quad], quad = 16B {hi x4, lo x4}
    __shared__ int4 Apk[2][64][16];   // A = W^T  (A[x][c] = W[c][x])
    __shared__ int4 Bpk[2][64][16];   // B = e    (B[c][y])

    const int t  = threadIdx.x;
    const int l  = t & 63;
    const int w  = t >> 6;        // wave 0..7
    const int cg = w & 3;         // column group: cols 16cg..16cg+15
    const int mh = w >> 2;        // m-half: this wave's m = 2*mh + mm
    const int rg = l >> 4;        // lane row-group 0..3
    const int cl = l & 15;        // lane col within tile
    const int Y  = (cg << 4) + cl;

    const float* S13  = S  + 13 * 4096;
    const float* S14  = S  + 14 * 4096;
    const float* Wk13 = Wk + 13 * 4096;

    // ================= ONE global-load burst (all cold loads) =============
    float s[2][4], Wc[2][4];
    float4 rsq[2];                 // Rs source rows
    float4 cb0[2], cb1[2];         // Wk13 row Y, kc=0/1
    float4 aq0[2][2], aq1[2][2];   // S14 A-rows [mm][kc]
    #pragma unroll
    for (int mm = 0; mm < 2; ++mm) {
        const int m = (mh << 1) + mm;
        #pragma unroll
        for (int r = 0; r < 4; ++r) {
            const int X = (m << 4) + (rg << 2) + r;
            s[mm][r]  = S13[X * 64 + Y];
            Wc[mm][r] = Wg[X * 64 + Y];
        }
        rsq[mm] = *(const float4*)(S14 + Y * 64 + (m << 4) + (rg << 2));
        #pragma unroll
        for (int kc = 0; kc < 2; ++kc) {
            const float* p = S14 + ((m << 4) + cl) * 64 + kc * 32 + rg * 8;
            aq0[mm][kc] = *(const float4*)p;
            aq1[mm][kc] = *(const float4*)(p + 4);
        }
    }
    #pragma unroll
    for (int kc = 0; kc < 2; ++kc) {
        const float* p = Wk13 + Y * 64 + kc * 32 + rg * 8;
        cb0[kc] = *(const float4*)p;
        cb1[kc] = *(const float4*)(p + 4);
    }

    float Rs[2][4];
    #pragma unroll
    for (int mm = 0; mm < 2; ++mm) {
        Rs[mm][0] = rsq[mm].x > 0.f ? LRc : 0.f;
        Rs[mm][1] = rsq[mm].y > 0.f ? LRc : 0.f;
        Rs[mm][2] = rsq[mm].z > 0.f ? LRc : 0.f;
        Rs[mm][3] = rsq[mm].w > 0.f ? LRc : 0.f;
    }

    // ---------- C = relu(S14) @ Wk13^T via 3-term split MFMA (once) --------
    bf16x8 cbh[2], cbm[2], cbl[2];
    #pragma unroll
    for (int kc = 0; kc < 2; ++kc) {
        float v[8] = {cb0[kc].x, cb0[kc].y, cb0[kc].z, cb0[kc].w,
                      cb1[kc].x, cb1[kc].y, cb1[kc].z, cb1[kc].w};
        split3pack8(v, cbh[kc], cbm[kc], cbl[kc]);
    }

    f32x4 Cacc[2];
    #pragma unroll
    for (int mm = 0; mm < 2; ++mm) Cacc[mm] = (f32x4){0.f, 0.f, 0.f, 0.f};

    #pragma unroll
    for (int mm = 0; mm < 2; ++mm) {
        #pragma unroll
        for (int kc = 0; kc < 2; ++kc) {
            float v[8] = {fmaxf(aq0[mm][kc].x, 0.f), fmaxf(aq0[mm][kc].y, 0.f),
                          fmaxf(aq0[mm][kc].z, 0.f), fmaxf(aq0[mm][kc].w, 0.f),
                          fmaxf(aq1[mm][kc].x, 0.f), fmaxf(aq1[mm][kc].y, 0.f),
                          fmaxf(aq1[mm][kc].z, 0.f), fmaxf(aq1[mm][kc].w, 0.f)};
            bf16x8 ah, am, al;
            split3pack8(v, ah, am, al);
            // products down to 2^-24: hh, hm, mh, mm, hl, lh
            Cacc[mm] = MFMA(ah, cbh[kc], Cacc[mm], 0, 0, 0);
            Cacc[mm] = MFMA(ah, cbm[kc], Cacc[mm], 0, 0, 0);
            Cacc[mm] = MFMA(am, cbh[kc], Cacc[mm], 0, 0, 0);
            Cacc[mm] = MFMA(am, cbm[kc], Cacc[mm], 0, 0, 0);
            Cacc[mm] = MFMA(ah, cbl[kc], Cacc[mm], 0, 0, 0);
            Cacc[mm] = MFMA(al, cbh[kc], Cacc[mm], 0, 0, 0);
        }
    }

    // ---------- 9 full cycles (cycle 10's matmul/s-update are dead) -------
    float e[2][4], wn[2][4];
    for (int it = 0; it < 9; ++it) {
        const int buf = it & 1;

        // e = s - C ; wn = e .* Rs ; stage W_t (transposed) and e_t.
        #pragma unroll
        for (int mm = 0; mm < 2; ++mm) {
            const int m = (mh << 1) + mm;
            #pragma unroll
            for (int r = 0; r < 4; ++r) {
                e[mm][r]  = s[mm][r] - Cacc[mm][r];
                wn[mm][r] = e[mm][r] * Rs[mm][r];
            }
            const int qw = ((m << 2) + rg) ^ cl;   // 16B-granular XOR swizzle
            Apk[buf][Y][qw] = split2pack(Wc[mm][0], Wc[mm][1], Wc[mm][2], Wc[mm][3]);
            Bpk[buf][Y][qw] = split2pack(e[mm][0],  e[mm][1],  e[mm][2],  e[mm][3]);
        }
        __syncthreads();

        // batched read burst: 12 ds_read_b128 (B x4, A x8 for this m-half)
        int4 br[2][2], arr[2][2][2];
        #pragma unroll
        for (int kc = 0; kc < 2; ++kc) {
            const int q0 = (kc << 3) + (rg << 1);
            br[kc][0] = Bpk[buf][Y][q0 ^ cl];
            br[kc][1] = Bpk[buf][Y][(q0 + 1) ^ cl];
            #pragma unroll
            for (int mm = 0; mm < 2; ++mm) {
                const int row = (((mh << 1) + mm) << 4) + cl;
                arr[kc][mm][0] = Apk[buf][row][q0 ^ cl];
                arr[kc][mm][1] = Apk[buf][row][(q0 + 1) ^ cl];
            }
        }

        // MFMA chain (per-accumulator order identical to R5-R7:
        // kc0 hh,hl,lh ; kc1 hh,hl,lh -> bit-identical numerics)
        f32x4 g[2];
        #pragma unroll
        for (int mm = 0; mm < 2; ++mm) g[mm] = (f32x4){0.f, 0.f, 0.f, 0.f};

        #pragma unroll
        for (int kc = 0; kc < 2; ++kc) {
            bf16x8 bh = mkfrag(br[kc][0].x, br[kc][0].y, br[kc][1].x, br[kc][1].y);
            bf16x8 bl = mkfrag(br[kc][0].z, br[kc][0].w, br[kc][1].z, br[kc][1].w);
            #pragma unroll
            for (int mm = 0; mm < 2; ++mm) {
                bf16x8 ah = mkfrag(arr[kc][mm][0].x, arr[kc][mm][0].y,
                                   arr[kc][mm][1].x, arr[kc][mm][1].y);
                bf16x8 al = mkfrag(arr[kc][mm][0].z, arr[kc][mm][0].w,
                                   arr[kc][mm][1].z, arr[kc][mm][1].w);
                g[mm] = MFMA(ah, bh, g[mm], 0, 0, 0);   // hh
                g[mm] = MFMA(ah, bl, g[mm], 0, 0, 0);   // hl
                g[mm] = MFMA(al, bh, g[mm], 0, 0, 0);   // lh
            }
        }

        // s += LR * (relu'(s) - e) .* g ; W_{t+1} = wn
        #pragma unroll
        for (int mm = 0; mm < 2; ++mm)
            #pragma unroll
            for (int r = 0; r < 4; ++r) {
                float rp = s[mm][r] > 0.f ? 1.f : 0.f;
                s[mm][r] = fmaf(LRc * (rp - e[mm][r]), g[mm][r], s[mm][r]);
                Wc[mm][r] = wn[mm][r];
            }
        // double-buffered; the single barrier per iter orders read(buf) at t
        // before write(buf) at t+2 (all waves pass barrier t+1 in between).
    }

    // ---------- tail (cycle 10): only wn is observable -------------------
    // out[4096:8192] = W after 10 cycles = (s9 - C) .* Rs, same op order.
    #pragma unroll
    for (int mm = 0; mm < 2; ++mm)
        #pragma unroll
        for (int r = 0; r < 4; ++r) {
            float ee = s[mm][r] - Cacc[mm][r];
            float ww = ee * Rs[mm][r];
            out[4096 + ((((mh << 1) + mm) << 4) + (rg << 2) + r) * 64 + Y] = ww;
        }
}

extern "C" void kernel_launch(void* const* d_in, const int* in_sizes, int n_in,
                              void* d_out, int out_size, void* d_ws, size_t ws_size,
                              hipStream_t stream) {
    const float* S  = (const float*)d_in[2];   // (15,64,64)
    const float* Wk = (const float*)d_in[4];   // (14,64,64)
    const float* Wg = (const float*)d_in[5];   // (64,64)
    float* out = (float*)d_out;                // 8192 floats
    pcn_kernel<<<2, 512, 0, stream>>>(S, Wk, Wg, out);
}